// Round 8
// baseline (2354.935 us; speedup 1.0000x reference)
//
#include <hip/hip_runtime.h>

// Hierarchical RNN — MFMA dataflow, v16 (bisection of v15's failure).
// v15 (per-wave flags + self-quarter-in-LDS) failed absmax 0.898 — a race,
// but static analysis can't convict either change. v16 isolates the flag
// protocol: v12's EXACT dataflow (all cols staged from slab every step,
// single lsO buffer, same MFMA/WAR/rdfl) with ONLY the sync changed:
//  - flags2[24 coh][32 waves]; producer wave publishes t+1 after its own
//    store->threadfence_block->flag (v11-proven primitive).
//  - consumers poll per-thread, only the producer wave of their column;
//    own-wg columns need NO poll (producer stores drained vmcnt(0) at its
//    barrier2, which the consumer also passed).
//  - 2 barriers/step (drop post-spin broadcast + post-store drain barriers).
// Pass => v15's self-LDS was the bug. Fail => per-wave flags are the bug.
// WAR/ring-4/rdfl byte-identical to v12.

#define TSTEPS 512
#define BATCH  128
#define DMOD   3
#define NH     512
#define CCLS   2
#define OUT2   (DMOD * BATCH * NH)

typedef unsigned long long u64;
typedef unsigned int u32;
typedef __attribute__((ext_vector_type(8))) short bf16x8;
typedef __attribute__((ext_vector_type(4))) float f32x4;

__device__ __forceinline__ float bflo(u32 u) { return __uint_as_float(u << 16); }
__device__ __forceinline__ float bfhi(u32 u) { return __uint_as_float(u & 0xffff0000u); }
__device__ __forceinline__ unsigned short f2bf(float x) {
    u32 u = __float_as_uint(x);
    return (unsigned short)((u + 0x7fffu + ((u >> 16) & 1u)) >> 16);
}
__device__ __forceinline__ u64 pack4bf(float a, float b, float c, float d) {
    u32 lo = (u32)f2bf(a) | ((u32)f2bf(b) << 16);
    u32 hi = (u32)f2bf(c) | ((u32)f2bf(d) << 16);
    return (u64)lo | ((u64)hi << 32);
}
__device__ __forceinline__ float lrelu(float x) { return fmaxf(x, 0.01f * x); }

__device__ __forceinline__ u64 ld_h(const u64* p) {
    return __hip_atomic_load(p, __ATOMIC_RELAXED, __HIP_MEMORY_SCOPE_AGENT);
}
__device__ __forceinline__ void st_h(u64* p, u64 v) {
    __hip_atomic_store(p, v, __ATOMIC_RELAXED, __HIP_MEMORY_SCOPE_AGENT);
}
__device__ __forceinline__ int ld_slot(const int* p) {
    return __hip_atomic_load(p, __ATOMIC_RELAXED, __HIP_MEMORY_SCOPE_AGENT);
}
__device__ __forceinline__ void st_slot(int* p, int v) {
    __hip_atomic_store(p, v, __ATOMIC_RELAXED, __HIP_MEMORY_SCOPE_AGENT);
}

__global__ __launch_bounds__(512, 2)
void rnn_mfma(const float* __restrict__ data,
              const float* __restrict__ h0,
              const float* __restrict__ W_in,
              const float* __restrict__ b_in,
              const float* __restrict__ W_hh,
              const float* __restrict__ b_hh,
              const float* __restrict__ W_ff,
              const float* __restrict__ b_ff,
              const float* __restrict__ taus,
              const float* __restrict__ W_fc,
              const float* __restrict__ b_fc,
              float* __restrict__ out,
              int* __restrict__ wsI)
{
    const int wgid = blockIdx.x;        // 0..95
    const int d    = wgid >> 5;         // 0..2
    const int rr   = wgid & 31;
    const int bt   = rr >> 2;           // 0..7 (16-row b-tile)
    const int q    = rr & 3;            // 0..3 (8-wave nt quarter)
    const int w    = threadIdx.x >> 6;  // wave 0..7
    const int lane = threadIdx.x & 63;
    const int nt   = q * 8 + w;         // 0..31 (16-col n-tile)
    const int colb = lane & 15;         // C col = local b
    const int quad = lane >> 4;         // 0..3
    const int b    = bt * 16 + colb;
    const int n0   = nt * 16 + quad * 4;

    int* flags2 = wsI;                       // [24 coh][32 waves] @0 (3KB)
    int* rdfl   = wsI + 1024;                // @4096 B: [96] wg read-progress
    u64* slab   = (u64*)((char*)wsI + 65536);// [4][3][128 b][128] u64 (bf16 h)

    __shared__ u64 lsO[2048];   // own-h tile [16 b][128 u64], XOR-swizzled
    __shared__ u64 lsF[2048];   // ff-h tile

    // ---- preload weights as A-fragments (A[m=lane&15][k=quad*8+j]) ----
    bf16x8 wOwn[16], wFf[16];
    {
        const int nrow = nt * 16 + colb;     // A m-index = n_out
        const float* gw = W_hh + ((size_t)d * NH + nrow) * NH;
        for (int kc = 0; kc < 16; ++kc) {
            int k0 = kc * 32 + quad * 8;
            union { unsigned short s[8]; bf16x8 v; } u;
            for (int j = 0; j < 8; ++j) {
                float x = gw[k0 + j];
                if (k0 + j == nrow) x = 0.f;   // zeroed diagonal
                u.s[j] = f2bf(x);
            }
            wOwn[kc] = u.v;
        }
        if (d > 0) {
            const float* gf = W_ff + ((size_t)(d - 1) * NH + nrow) * NH;
            for (int kc = 0; kc < 16; ++kc) {
                int k0 = kc * 32 + quad * 8;
                union { unsigned short s[8]; bf16x8 v; } u;
                for (int j = 0; j < 8; ++j) u.s[j] = f2bf(gf[k0 + j]);
                wFf[kc] = u.v;
            }
        }
    }

    // finalize constants for this lane's 4 n
    float wi4[4], cb4[4], al4[4], it4[4];
#pragma unroll
    for (int k = 0; k < 4; ++k) {
        int n = n0 + k;
        wi4[k] = W_in[d * NH + n];
        float cbv = b_hh[d * NH + n] + b_in[d * NH + n];
        if (d > 0) cbv += b_ff[(d - 1) * NH + n];
        cb4[k] = cbv;
        float tc = fmaxf(taus[d * NH + n], 1.0f);
        it4[k] = 1.0f / tc;
        al4[k] = 1.0f - it4[k];
    }

    const int coh = d * 8 + bt;              // cohort 0..23
    int* f2my = flags2 + coh * 32 + nt;      // MY WAVE's flag

    const int cohBaseR = d * 32 + bt * 4;    // rdfl wg-granular (as v12)
    const int l3 = lane & 3;
    int* rmy = rdfl + cohBaseR + q;
    const int* rOwn = rdfl + cohBaseR + l3;
    const int* rUp  = rdfl + (d < DMOD - 1 ? cohBaseR + 32 : cohBaseR) + l3;

    const int scol = threadIdx.x & 127;      // u64 col within 1KB row
    const int sr0  = threadIdx.x >> 7;       // row group 0..3
    const int cA   = scol ^ (sr0 << 1);            // swz rows sr0, sr0+8
    const int cB   = scol ^ ((sr0 + 4) << 1);      // swz rows sr0+4, sr0+12
    const bool isSelf = ((scol >> 5) == q);        // own-wg producer column
    const int pw = scol >> 2;                      // producer wave for my col
    const int* fOw = flags2 + coh * 32 + pw;
    const int* fLw = flags2 + (d > 0 ? (coh - 8) : coh) * 32 + pw;

    u64 prev = 0;

    for (int t = 0; t < TSTEPS; ++t) {
        // ---- per-thread dep poll: foreign own-cohort wave >= t, ff >= t+1.
        // Own-wg columns need no poll: producer stores drained (vmcnt 0) at
        // its barrier2 of step t-1, which this thread also passed.
        const bool needO = (t > 0) && !isSelf;
        const bool needF = (d > 0);
        if (needO || needF) {
            while (1) {
                bool ok = true;
                if (needO) ok = (ld_slot(fOw) >= t);
                if (needF) ok = ok && (ld_slot(fLw) >= t + 1);
                if (__all(ok)) break;
                __builtin_amdgcn_s_sleep(1);
            }
            asm volatile("" ::: "memory");
        }

        // ---- cooperative stage: own h(t-1) (ALL cols) + ff h_{d-1}(t) ----
        if (t == 0) {
            const float* hp = h0 + ((size_t)(d * BATCH) + bt * 16) * NH;
            float4 x0 = *(const float4*)(hp + (size_t)(sr0     ) * NH + scol * 4);
            float4 x1 = *(const float4*)(hp + (size_t)(sr0 +  4) * NH + scol * 4);
            float4 x2 = *(const float4*)(hp + (size_t)(sr0 +  8) * NH + scol * 4);
            float4 x3 = *(const float4*)(hp + (size_t)(sr0 + 12) * NH + scol * 4);
            lsO[(sr0     ) * 128 + cA] = pack4bf(x0.x, x0.y, x0.z, x0.w);
            lsO[(sr0 +  4) * 128 + cB] = pack4bf(x1.x, x1.y, x1.z, x1.w);
            lsO[(sr0 +  8) * 128 + cA] = pack4bf(x2.x, x2.y, x2.z, x2.w);
            lsO[(sr0 + 12) * 128 + cB] = pack4bf(x3.x, x3.y, x3.z, x3.w);
        } else {
            const u64* sp = slab + (((size_t)((t - 1) & 3) * 3 + d) << 14)
                          + (size_t)(bt * 16) * 128 + scol;
            u64 v0 = ld_h(sp + (size_t)(sr0     ) * 128);
            u64 v1 = ld_h(sp + (size_t)(sr0 +  4) * 128);
            u64 v2 = ld_h(sp + (size_t)(sr0 +  8) * 128);
            u64 v3 = ld_h(sp + (size_t)(sr0 + 12) * 128);
            lsO[(sr0     ) * 128 + cA] = v0;
            lsO[(sr0 +  4) * 128 + cB] = v1;
            lsO[(sr0 +  8) * 128 + cA] = v2;
            lsO[(sr0 + 12) * 128 + cB] = v3;
        }
        if (d > 0) {
            const u64* gp = slab + (((size_t)(t & 3) * 3 + (d - 1)) << 14)
                          + (size_t)(bt * 16) * 128 + scol;
            u64 v0 = ld_h(gp + (size_t)(sr0     ) * 128);
            u64 v1 = ld_h(gp + (size_t)(sr0 +  4) * 128);
            u64 v2 = ld_h(gp + (size_t)(sr0 +  8) * 128);
            u64 v3 = ld_h(gp + (size_t)(sr0 + 12) * 128);
            lsF[(sr0     ) * 128 + cA] = v0;
            lsF[(sr0 +  4) * 128 + cB] = v1;
            lsF[(sr0 +  8) * 128 + cA] = v2;
            lsF[(sr0 + 12) * 128 + cB] = v3;
        }
        float xs = data[t * BATCH + b];      // hoisted input load
        __syncthreads();   // barrier1: LDS tiles complete (vmcnt+lgkm drained)
        if (w == 0 && lane == 0) st_slot(rmy, t);   // wg slab-reads done

        // ---- MFMA from LDS: C[m=n_out][n=b], 16 own + 16 ff ----
        f32x4 acc = {0.f, 0.f, 0.f, 0.f};
        const int swz = (colb & 7) << 1;
        const int cq  = quad * 2;
        const u64* bO = lsO + (size_t)colb * 128;
#pragma unroll
        for (int kc = 0; kc < 16; ++kc) {
            bf16x8 bv = *(const bf16x8*)(bO + (((kc * 8 + cq) ^ swz)));
            acc = __builtin_amdgcn_mfma_f32_16x16x32_bf16(wOwn[kc], bv, acc, 0, 0, 0);
        }
        if (d > 0) {
            const u64* bF = lsF + (size_t)colb * 128;
#pragma unroll
            for (int kc = 0; kc < 16; ++kc) {
                bf16x8 bv = *(const bf16x8*)(bF + (((kc * 8 + cq) ^ swz)));
                acc = __builtin_amdgcn_mfma_f32_16x16x32_bf16(wFf[kc], bv, acc, 0, 0, 0);
            }
        }

        // ---- finalize (lane-local: 4 n for its b) ----
        float h0f, h1f, h2f, h3f;
        if (t == 0) {
            float4 v = *(const float4*)(h0 + ((size_t)(d * BATCH) + b) * NH + n0);
            h0f = v.x; h1f = v.y; h2f = v.z; h3f = v.w;
        } else {
            h0f = bflo((u32)prev);         h1f = bfhi((u32)prev);
            h2f = bflo((u32)(prev >> 32)); h3f = bfhi((u32)(prev >> 32));
        }
        float p0 = acc.x + cb4[0] + xs * wi4[0];
        float p1 = acc.y + cb4[1] + xs * wi4[1];
        float p2 = acc.z + cb4[2] + xs * wi4[2];
        float p3 = acc.w + cb4[3] + xs * wi4[3];
        float n0v = al4[0] * h0f + lrelu(p0) * it4[0];
        float n1v = al4[1] * h1f + lrelu(p1) * it4[1];
        float n2v = al4[2] * h2f + lrelu(p2) * it4[2];
        float n3v = al4[3] * h3f + lrelu(p3) * it4[3];
        u64 pk = pack4bf(n0v, n1v, n2v, n3v);
        prev = pk;

        // ---- WAR guard (ring-4 slack; wave 0 polls, normally instant) ----
        if (w == 0 && t >= 4) {
            while (1) {
                bool ok = true;
                if (lane < 4) ok = (ld_slot(rOwn) >= t - 3);
                else if (lane < 8) { if (d < DMOD - 1) ok = (ld_slot(rUp) >= t - 4); }
                if (__all(ok)) break;
                __builtin_amdgcn_s_sleep(1);
            }
        }
        __syncthreads();   // barrier2: WAR cleared; prev-step LDS reads done

        st_h(slab + (((size_t)(t & 3) * 3 + d) << 14)
             + (size_t)b * 128 + (size_t)nt * 4 + quad, pk);
        if (t == TSTEPS - 1) {
            *(float4*)(out + ((size_t)(d * BATCH) + b) * NH + n0)
                = make_float4(n0v, n1v, n2v, n3v);
        }
        __threadfence_block();               // v11-proven: drain, then flag
        if (lane == 0) st_slot(f2my, t + 1); // PER-WAVE publish (no barrier)
    }

    // ---- readout heads: wg q==0 wave 0; lane<32 -> (b=lane&15, c=lane>>4) -
    if (q == 0 && w == 0) {
        const int* fAll = flags2 + coh * 32 + (lane & 31);
        while (1) {
            bool ok = true;
            if (lane < 32) ok = (ld_slot(fAll) >= TSTEPS);
            if (__all(ok)) break;
            __builtin_amdgcn_s_sleep(2);
        }
        asm volatile("" ::: "memory");
        if (lane < 32) {
            const int bb = bt * 16 + (lane & 15);
            const int c  = (lane >> 4) & 1;
            const u64* hf = slab + (((size_t)3 * 3 + d) << 14) + (size_t)bb * 128;
            const float4* wf = (const float4*)(W_fc + ((size_t)(d * CCLS) + c) * NH);
            float s = b_fc[d * CCLS + c];
            for (int q2 = 0; q2 < 128; ++q2) {
                u64 u = ld_h(hf + q2);
                float4 ww = wf[q2];
                s += bflo((u32)u) * ww.x + bfhi((u32)u) * ww.y
                   + bflo((u32)(u >> 32)) * ww.z + bfhi((u32)(u >> 32)) * ww.w;
            }
            out[OUT2 + (size_t)(d * BATCH + bb) * CCLS + c] = s;
        }
    }
}

extern "C" void kernel_launch(void* const* d_in, const int* in_sizes, int n_in,
                              void* d_out, int out_size, void* d_ws, size_t ws_size,
                              hipStream_t stream) {
    const float* data = (const float*)d_in[0];
    const float* h0   = (const float*)d_in[1];
    const float* W_in = (const float*)d_in[2];
    const float* b_in = (const float*)d_in[3];
    const float* W_hh = (const float*)d_in[4];
    const float* b_hh = (const float*)d_in[5];
    const float* W_ff = (const float*)d_in[6];
    const float* b_ff = (const float*)d_in[7];
    const float* taus = (const float*)d_in[8];
    const float* W_fc = (const float*)d_in[9];
    const float* b_fc = (const float*)d_in[10];

    // no init: flags2/rdfl poison 0xAAAAAAAA reads negative = "not done".
    hipLaunchKernelGGL(rnn_mfma, dim3(96), dim3(512), 0, stream,
                       data, h0, W_in, b_in, W_hh, b_hh, W_ff, b_ff,
                       taus, W_fc, b_fc, (float*)d_out, (int*)d_ws);
}

// Round 9
// 1686.009 us; speedup vs baseline: 1.3968x; 1.3968x over previous
//
#include <hip/hip_runtime.h>

// Hierarchical RNN — MFMA dataflow, v17: tag-in-data exchange.
// Bisection (r8): v16 (per-wave flags, 2 barriers) == v12 time => step time is
// cross-wg exchange LATENCY (flag-observe MALL trip + data-load MALL trip),
// not barriers. v17 merges the two trips: the LSB of each bf16 in a slab u64
// carries the generation parity tag ((t>>2)&1)^1 — ring-4 slot holds gen t or
// t-4, whose tags always differ; workspace poison 0xAAAA has LSB 0 = invalid
// for t<4. Consumers poll the DATA (load == sync). This also closes:
//  - v16's latent same-wg store->load race on self columns (now validated);
//  - v15's suspected payload/flag relaxed-store reorder (no flags left).
// rdfl/WAR ring-4 byte-identical to v12/v16. Readout uses a dedicated fresh
// 'fin' region (tag=1, poison-safe, no slot-generation aliasing).
// Cost: 1-ulp LSB stomp on exchanged h (absmax 0.031 -> <=0.0625, thr 0.19).

#define TSTEPS 512
#define BATCH  128
#define DMOD   3
#define NH     512
#define CCLS   2
#define OUT2   (DMOD * BATCH * NH)
#define LSBPAT 0x0001000100010001ULL

typedef unsigned long long u64;
typedef unsigned int u32;
typedef __attribute__((ext_vector_type(8))) short bf16x8;
typedef __attribute__((ext_vector_type(4))) float f32x4;

__device__ __forceinline__ float bflo(u32 u) { return __uint_as_float(u << 16); }
__device__ __forceinline__ float bfhi(u32 u) { return __uint_as_float(u & 0xffff0000u); }
__device__ __forceinline__ unsigned short f2bf(float x) {
    u32 u = __float_as_uint(x);
    return (unsigned short)((u + 0x7fffu + ((u >> 16) & 1u)) >> 16);
}
__device__ __forceinline__ u64 pack4bf(float a, float b, float c, float d) {
    u32 lo = (u32)f2bf(a) | ((u32)f2bf(b) << 16);
    u32 hi = (u32)f2bf(c) | ((u32)f2bf(d) << 16);
    return (u64)lo | ((u64)hi << 32);
}
__device__ __forceinline__ float lrelu(float x) { return fmaxf(x, 0.01f * x); }

__device__ __forceinline__ u64 ld_h(const u64* p) {
    return __hip_atomic_load(p, __ATOMIC_RELAXED, __HIP_MEMORY_SCOPE_AGENT);
}
__device__ __forceinline__ void st_h(u64* p, u64 v) {
    __hip_atomic_store(p, v, __ATOMIC_RELAXED, __HIP_MEMORY_SCOPE_AGENT);
}
__device__ __forceinline__ int ld_slot(const int* p) {
    return __hip_atomic_load(p, __ATOMIC_RELAXED, __HIP_MEMORY_SCOPE_AGENT);
}
__device__ __forceinline__ void st_slot(int* p, int v) {
    __hip_atomic_store(p, v, __ATOMIC_RELAXED, __HIP_MEMORY_SCOPE_AGENT);
}

__global__ __launch_bounds__(512, 2)
void rnn_mfma(const float* __restrict__ data,
              const float* __restrict__ h0,
              const float* __restrict__ W_in,
              const float* __restrict__ b_in,
              const float* __restrict__ W_hh,
              const float* __restrict__ b_hh,
              const float* __restrict__ W_ff,
              const float* __restrict__ b_ff,
              const float* __restrict__ taus,
              const float* __restrict__ W_fc,
              const float* __restrict__ b_fc,
              float* __restrict__ out,
              int* __restrict__ wsI)
{
    const int wgid = blockIdx.x;        // 0..95
    const int d    = wgid >> 5;         // 0..2
    const int rr   = wgid & 31;
    const int bt   = rr >> 2;           // 0..7 (16-row b-tile)
    const int q    = rr & 3;            // 0..3 (8-wave nt quarter)
    const int w    = threadIdx.x >> 6;  // wave 0..7
    const int lane = threadIdx.x & 63;
    const int nt   = q * 8 + w;         // 0..31 (16-col n-tile)
    const int colb = lane & 15;         // C col = local b
    const int quad = lane >> 4;         // 0..3
    const int b    = bt * 16 + colb;
    const int n0   = nt * 16 + quad * 4;

    int* rdfl = wsI + 1024;                  // @4096 B: [96] wg read-progress
    u64* slab = (u64*)((char*)wsI + 65536);  // [4][3][128 b][128] u64 (tagged)
    u64* fin  = slab + ((size_t)12 << 14);   // [3][128 b][128] final h, tag=1

    __shared__ u64 lsO[2048];   // own-h tile [16 b][128 u64], XOR-swizzled
    __shared__ u64 lsF[2048];   // ff-h tile

    // ---- preload weights as A-fragments (A[m=lane&15][k=quad*8+j]) ----
    bf16x8 wOwn[16], wFf[16];
    {
        const int nrow = nt * 16 + colb;     // A m-index = n_out
        const float* gw = W_hh + ((size_t)d * NH + nrow) * NH;
        for (int kc = 0; kc < 16; ++kc) {
            int k0 = kc * 32 + quad * 8;
            union { unsigned short s[8]; bf16x8 v; } u;
            for (int j = 0; j < 8; ++j) {
                float x = gw[k0 + j];
                if (k0 + j == nrow) x = 0.f;   // zeroed diagonal
                u.s[j] = f2bf(x);
            }
            wOwn[kc] = u.v;
        }
        if (d > 0) {
            const float* gf = W_ff + ((size_t)(d - 1) * NH + nrow) * NH;
            for (int kc = 0; kc < 16; ++kc) {
                int k0 = kc * 32 + quad * 8;
                union { unsigned short s[8]; bf16x8 v; } u;
                for (int j = 0; j < 8; ++j) u.s[j] = f2bf(gf[k0 + j]);
                wFf[kc] = u.v;
            }
        }
    }

    // finalize constants for this lane's 4 n
    float wi4[4], cb4[4], al4[4], it4[4];
#pragma unroll
    for (int k = 0; k < 4; ++k) {
        int n = n0 + k;
        wi4[k] = W_in[d * NH + n];
        float cbv = b_hh[d * NH + n] + b_in[d * NH + n];
        if (d > 0) cbv += b_ff[(d - 1) * NH + n];
        cb4[k] = cbv;
        float tc = fmaxf(taus[d * NH + n], 1.0f);
        it4[k] = 1.0f / tc;
        al4[k] = 1.0f - it4[k];
    }

    const int cohBaseR = d * 32 + bt * 4;    // rdfl wg-granular (as v12)
    const int l3 = lane & 3;
    int* rmy = rdfl + cohBaseR + q;
    const int* rOwn = rdfl + cohBaseR + l3;
    const int* rUp  = rdfl + (d < DMOD - 1 ? cohBaseR + 32 : cohBaseR) + l3;

    const int scol = threadIdx.x & 127;      // u64 col within 1KB row
    const int sr0  = threadIdx.x >> 7;       // row group 0..3
    const int cA   = scol ^ (sr0 << 1);            // swz rows sr0, sr0+8
    const int cB   = scol ^ ((sr0 + 4) << 1);      // swz rows sr0+4, sr0+12

    u64 prev = 0;

    for (int t = 0; t < TSTEPS; ++t) {
        // ---- stage own h(t-1): tag-validated loads (load == sync) ----
        if (t == 0) {
            const float* hp = h0 + ((size_t)(d * BATCH) + bt * 16) * NH;
            float4 x0 = *(const float4*)(hp + (size_t)(sr0     ) * NH + scol * 4);
            float4 x1 = *(const float4*)(hp + (size_t)(sr0 +  4) * NH + scol * 4);
            float4 x2 = *(const float4*)(hp + (size_t)(sr0 +  8) * NH + scol * 4);
            float4 x3 = *(const float4*)(hp + (size_t)(sr0 + 12) * NH + scol * 4);
            lsO[(sr0     ) * 128 + cA] = pack4bf(x0.x, x0.y, x0.z, x0.w);
            lsO[(sr0 +  4) * 128 + cB] = pack4bf(x1.x, x1.y, x1.z, x1.w);
            lsO[(sr0 +  8) * 128 + cA] = pack4bf(x2.x, x2.y, x2.z, x2.w);
            lsO[(sr0 + 12) * 128 + cB] = pack4bf(x3.x, x3.y, x3.z, x3.w);
        } else {
            const u64* sp = slab + (((size_t)((t - 1) & 3) * 3 + d) << 14)
                          + (size_t)(bt * 16) * 128 + scol;
            const u64 ex = (((((t - 1) >> 2) & 1) ^ 1) != 0) ? LSBPAT : 0ULL;
            u64 v0, v1, v2, v3;
            while (1) {
                v0 = ld_h(sp + (size_t)(sr0     ) * 128);
                v1 = ld_h(sp + (size_t)(sr0 +  4) * 128);
                v2 = ld_h(sp + (size_t)(sr0 +  8) * 128);
                v3 = ld_h(sp + (size_t)(sr0 + 12) * 128);
                u64 bad = ((v0 ^ ex) | (v1 ^ ex) | (v2 ^ ex) | (v3 ^ ex)) & LSBPAT;
                if (__all(bad == 0)) break;
                __builtin_amdgcn_s_sleep(1);
            }
            lsO[(sr0     ) * 128 + cA] = v0;
            lsO[(sr0 +  4) * 128 + cB] = v1;
            lsO[(sr0 +  8) * 128 + cA] = v2;
            lsO[(sr0 + 12) * 128 + cB] = v3;
        }
        // ---- stage ff h_{d-1}(t): tag-validated ----
        if (d > 0) {
            const u64* gp = slab + (((size_t)(t & 3) * 3 + (d - 1)) << 14)
                          + (size_t)(bt * 16) * 128 + scol;
            const u64 ex = ((((t >> 2) & 1) ^ 1) != 0) ? LSBPAT : 0ULL;
            u64 v0, v1, v2, v3;
            while (1) {
                v0 = ld_h(gp + (size_t)(sr0     ) * 128);
                v1 = ld_h(gp + (size_t)(sr0 +  4) * 128);
                v2 = ld_h(gp + (size_t)(sr0 +  8) * 128);
                v3 = ld_h(gp + (size_t)(sr0 + 12) * 128);
                u64 bad = ((v0 ^ ex) | (v1 ^ ex) | (v2 ^ ex) | (v3 ^ ex)) & LSBPAT;
                if (__all(bad == 0)) break;
                __builtin_amdgcn_s_sleep(1);
            }
            lsF[(sr0     ) * 128 + cA] = v0;
            lsF[(sr0 +  4) * 128 + cB] = v1;
            lsF[(sr0 +  8) * 128 + cA] = v2;
            lsF[(sr0 + 12) * 128 + cB] = v3;
        }
        float xs = data[t * BATCH + b];      // hoisted input load
        __syncthreads();   // barrier1: LDS tiles complete
        if (w == 0 && lane == 0) st_slot(rmy, t);   // wg slab-reads done

        // ---- MFMA from LDS: C[m=n_out][n=b], 16 own + 16 ff ----
        f32x4 acc = {0.f, 0.f, 0.f, 0.f};
        const int swz = (colb & 7) << 1;
        const int cq  = quad * 2;
        const u64* bO = lsO + (size_t)colb * 128;
#pragma unroll
        for (int kc = 0; kc < 16; ++kc) {
            bf16x8 bv = *(const bf16x8*)(bO + (((kc * 8 + cq) ^ swz)));
            acc = __builtin_amdgcn_mfma_f32_16x16x32_bf16(wOwn[kc], bv, acc, 0, 0, 0);
        }
        if (d > 0) {
            const u64* bF = lsF + (size_t)colb * 128;
#pragma unroll
            for (int kc = 0; kc < 16; ++kc) {
                bf16x8 bv = *(const bf16x8*)(bF + (((kc * 8 + cq) ^ swz)));
                acc = __builtin_amdgcn_mfma_f32_16x16x32_bf16(wFf[kc], bv, acc, 0, 0, 0);
            }
        }

        // ---- finalize (lane-local: 4 n for its b) ----
        float h0f, h1f, h2f, h3f;
        if (t == 0) {
            float4 v = *(const float4*)(h0 + ((size_t)(d * BATCH) + b) * NH + n0);
            h0f = v.x; h1f = v.y; h2f = v.z; h3f = v.w;
        } else {
            h0f = bflo((u32)prev);         h1f = bfhi((u32)prev);
            h2f = bflo((u32)(prev >> 32)); h3f = bfhi((u32)(prev >> 32));
        }
        float p0 = acc.x + cb4[0] + xs * wi4[0];
        float p1 = acc.y + cb4[1] + xs * wi4[1];
        float p2 = acc.z + cb4[2] + xs * wi4[2];
        float p3 = acc.w + cb4[3] + xs * wi4[3];
        float n0v = al4[0] * h0f + lrelu(p0) * it4[0];
        float n1v = al4[1] * h1f + lrelu(p1) * it4[1];
        float n2v = al4[2] * h2f + lrelu(p2) * it4[2];
        float n3v = al4[3] * h3f + lrelu(p3) * it4[3];
        u64 pk = pack4bf(n0v, n1v, n2v, n3v);
        pk = (pk & ~LSBPAT) | ((((t >> 2) & 1) ^ 1) != 0 ? LSBPAT : 0ULL);
        prev = pk;    // state consistent with what consumers see

        // ---- WAR guard (ring-4 slack; wave 0 polls, normally instant) ----
        if (w == 0 && t >= 4) {
            while (1) {
                bool ok = true;
                if (lane < 4) ok = (ld_slot(rOwn) >= t - 3);
                else if (lane < 8) { if (d < DMOD - 1) ok = (ld_slot(rUp) >= t - 4); }
                if (__all(ok)) break;
                __builtin_amdgcn_s_sleep(1);
            }
        }
        __syncthreads();   // barrier2: WAR cleared; LDS reads of this step done

        st_h(slab + (((size_t)(t & 3) * 3 + d) << 14)
             + (size_t)b * 128 + (size_t)nt * 4 + quad, pk);
        if (t == TSTEPS - 1) {
            *(float4*)(out + ((size_t)(d * BATCH) + b) * NH + n0)
                = make_float4(n0v, n1v, n2v, n3v);
            st_h(fin + ((size_t)d << 14) + (size_t)b * 128 + (size_t)nt * 4 + quad,
                 pk | LSBPAT);   // fresh region, tag=1 (poison LSB=0 invalid)
        }
        // no flag, no fence: consumers validate the data itself
    }

    // ---- readout heads: wg q==0 wave 0; lane<32 -> (b=lane&15, c=lane>>4) -
    if (q == 0 && w == 0 && lane < 32) {
        const int bb = bt * 16 + (lane & 15);
        const int c  = (lane >> 4) & 1;
        const u64* hf = fin + ((size_t)d << 14) + (size_t)bb * 128;
        const float4* wf = (const float4*)(W_fc + ((size_t)(d * CCLS) + c) * NH);
        float s = b_fc[d * CCLS + c];
        for (int q2 = 0; q2 < 128; ++q2) {
            u64 u;
            while (((u = ld_h(hf + q2)) & LSBPAT) != LSBPAT)
                __builtin_amdgcn_s_sleep(1);
            float4 ww = wf[q2];
            s += bflo((u32)u) * ww.x + bfhi((u32)u) * ww.y
               + bflo((u32)(u >> 32)) * ww.z + bfhi((u32)(u >> 32)) * ww.w;
        }
        out[OUT2 + (size_t)(d * BATCH + bb) * CCLS + c] = s;
    }
}

extern "C" void kernel_launch(void* const* d_in, const int* in_sizes, int n_in,
                              void* d_out, int out_size, void* d_ws, size_t ws_size,
                              hipStream_t stream) {
    const float* data = (const float*)d_in[0];
    const float* h0   = (const float*)d_in[1];
    const float* W_in = (const float*)d_in[2];
    const float* b_in = (const float*)d_in[3];
    const float* W_hh = (const float*)d_in[4];
    const float* b_hh = (const float*)d_in[5];
    const float* W_ff = (const float*)d_in[6];
    const float* b_ff = (const float*)d_in[7];
    const float* taus = (const float*)d_in[8];
    const float* W_fc = (const float*)d_in[9];
    const float* b_fc = (const float*)d_in[10];

    // no init needed: workspace poison 0xAAAAAAAA => rdfl negative ("not
    // done"), slab/fin bf16 LSBs = 0 (invalid for the tags that matter).
    hipLaunchKernelGGL(rnn_mfma, dim3(96), dim3(512), 0, stream,
                       data, h0, W_in, b_in, W_hh, b_hh, W_ff, b_ff,
                       taus, W_fc, b_fc, (float*)d_out, (int*)d_ws);
}